// Round 12
// baseline (175.241 us; speedup 1.0000x reference)
//
#include <hip/hip_runtime.h>
#include <math.h>

// B=2048, S=8, D=1280, K=1 rank-1 common-mode removal.
// R12 (resubmit; R11-round bench was a broker acquisition timeout).
// R11 post-mortem -- VGPR_Count=152 vs ~280 true live set: the
// f[8][5] register-held batch was spilled/re-materialized by the compiler,
// injecting scratch latency into the serial eigen chain (waves lived
// ~27us; occupancy avg 3/CU; everything <25% busy). Fix both causes:
//  (a) STREAM the gram (8 x float2 per chunk, accumulate, discard) and
//      RE-READ feat for apply (L3-resident: R11 FETCH=41MB < input proves
//      L3 serves re-reads). Live set ~190 -> no spill under (128,2) cap.
//  (b) 2 waves per batch (D-halves, 640 cols each): 4096 waves = 2
//      generations @ 8 waves/CU. 52-float partial-gram exchange via LDS,
//      two 2-wave barriers (cheap, no R9-style 4-wave+45KB phase lock).
// Eigen (proven R11 math, verbatim) on wave 0 only; wave 1 idles ~3us at
// the barrier, overlapped by other resident blocks.

#define SV 8
#define DV 1280
#define BSTRIDE (SV*DV)    // 10240 floats per batch
#define HALF 640           // per-wave D-half
#define NCH 5              // 128-float chunks per half (64 lanes x float2)

__device__ __forceinline__ float wsum(float v) {
    v += __shfl_xor(v, 32);
    v += __shfl_xor(v, 16);
    v += __shfl_xor(v, 8);
    v += __shfl_xor(v, 4);
    v += __shfl_xor(v, 2);
    v += __shfl_xor(v, 1);
    return v;
}

// constant-index upper-triangle accessors (i,k compile-time constants)
#define GU(i,k) ((i) <= (k) ? G[i][k] : G[k][i])
#define AU(i,k) ((i) <= (k) ? A[i][k] : A[k][i])

__global__ __launch_bounds__(128, 2)
void cmr_dual(const float* __restrict__ feat,
              const float* __restrict__ kp,
              const float* __restrict__ cmr_gate,
              float* __restrict__ out, int Bn)
{
    __shared__ float xch[52];    // wave1 partial: G upper-tri 44 + S 8
    __shared__ float cf[17];     // av[8], cv[8], bc

    const int tid  = threadIdx.x;
    const int lane = tid & 63;
    const int w    = tid >> 6;             // 0/1: D-half owner
    const int b    = blockIdx.x;           // 1 batch per block

    const float* __restrict__ fb =
        feat + (size_t)b * BSTRIDE + w * HALF + lane * 2;

    // ---- streamed per-lane gram partials over this wave's D-half ----
    float G[8][8];                          // only j>=i written
    float S[8];
#pragma unroll
    for (int i = 0; i < 8; ++i) {
        S[i] = 0.f;
#pragma unroll
        for (int j = i; j < 8; ++j) G[i][j] = 0.f;
    }
#pragma unroll
    for (int c = 0; c < NCH; ++c) {
        float2 x[8];
#pragma unroll
        for (int s = 0; s < 8; ++s)
            x[s] = *(const float2*)(fb + (size_t)s * DV + c * 128);
#pragma unroll
        for (int i = 0; i < 8; ++i) {
            S[i] += x[i].x + x[i].y;
#pragma unroll
            for (int j = i; j < 8; ++j)
                G[i][j] = fmaf(x[i].x, x[j].x,
                          fmaf(x[i].y, x[j].y, G[i][j]));
        }
    }
    // ---- butterfly: every lane gets this wave's half-D sums ----
#pragma unroll
    for (int i = 0; i < 8; ++i) {
        S[i] = wsum(S[i]);
#pragma unroll
        for (int j = i; j < 8; ++j) G[i][j] = wsum(G[i][j]);
    }

    // ---- wave1 publishes its partial ----
    if (w == 1 && lane == 0) {
        int p = 0;
#pragma unroll
        for (int i = 0; i < 8; ++i)
#pragma unroll
            for (int j = i; j < 8; ++j) { xch[p] = G[i][j]; ++p; }
#pragma unroll
        for (int i = 0; i < 8; ++i) xch[44 + i] = S[i];
    }
    __syncthreads();

    // ---- wave0: combine halves, eigen (proven R11 math), publish coeffs ----
    if (w == 0) {
        {
            int p = 0;
#pragma unroll
            for (int i = 0; i < 8; ++i)
#pragma unroll
                for (int j = i; j < 8; ++j) { G[i][j] += xch[p]; ++p; }
#pragma unroll
            for (int i = 0; i < 8; ++i) S[i] += xch[44 + i];
        }

        float mu[8], sig[8], rsig[8];
        const float invD = 1.f / (float)DV;
#pragma unroll
        for (int i = 0; i < 8; ++i) {
            mu[i] = S[i] * invD;
            const float var = fmaxf(G[i][i] * invD - mu[i] * mu[i], 0.f);
            sig[i]  = sqrtf(var) + 1e-8f;       // numpy std(ddof=0)+1e-8
            rsig[i] = 1.f / sig[i];
        }
#pragma unroll
        for (int i = 0; i < 8; ++i)
#pragma unroll
            for (int j = i; j < 8; ++j)
                G[i][j] = (G[i][j] - (float)DV * mu[i] * mu[j]) * rsig[i] * rsig[j];

        float tr = 0.f;
#pragma unroll
        for (int i = 0; i < 8; ++i) tr += G[i][i];

        // ---- 12x symmetric trace-normalized squaring (upper triangle) ----
        float A[8][8];
        {
            const float rt = 1.f / fmaxf(tr, 1e-30f);
#pragma unroll
            for (int i = 0; i < 8; ++i)
#pragma unroll
                for (int j = i; j < 8; ++j) A[i][j] = G[i][j] * rt;
        }
#pragma unroll
        for (int t = 0; t < 12; ++t) {
            float Bm[8][8];
            float trB = 0.f;
#pragma unroll
            for (int i = 0; i < 8; ++i)
#pragma unroll
                for (int j = i; j < 8; ++j) {
                    float acc = 0.f;
#pragma unroll
                    for (int k = 0; k < 8; ++k)
                        acc = fmaf(AU(i, k), AU(j, k), acc);   // A symmetric
                    Bm[i][j] = acc;
                    if (i == j) trB += acc;
                }
            const float rt = 1.f / fmaxf(trB, 1e-30f);
#pragma unroll
            for (int i = 0; i < 8; ++i)
#pragma unroll
                for (int j = i; j < 8; ++j) A[i][j] = Bm[i][j] * rt;
        }
        // diag argmax -> dominant column ~ u1 (A ~= u u^T)
        int bj = 0; float best = A[0][0];
#pragma unroll
        for (int k = 1; k < 8; ++k)
            if (A[k][k] > best) { best = A[k][k]; bj = k; }
        float u[8];
#pragma unroll
        for (int i = 0; i < 8; ++i) {
            float v = AU(i, 0);
#pragma unroll
            for (int k = 1; k < 8; ++k) v = (bj == k) ? AU(i, k) : v;
            u[i] = v;
        }
        {
            float nn = 0.f;
#pragma unroll
            for (int i = 0; i < 8; ++i) nn = fmaf(u[i], u[i], nn);
            const float r = rsqrtf(fmaxf(nn, 1e-30f));
#pragma unroll
            for (int i = 0; i < 8; ++i) u[i] *= r;
        }
        // 2 power-iteration polish steps on G
#pragma unroll
        for (int it = 0; it < 2; ++it) {
            float y[8]; float ny = 0.f;
#pragma unroll
            for (int i = 0; i < 8; ++i) {
                float acc = 0.f;
#pragma unroll
                for (int k = 0; k < 8; ++k) acc = fmaf(GU(i, k), u[k], acc);
                y[i] = acc; ny = fmaf(acc, acc, ny);
            }
            const float r = rsqrtf(fmaxf(ny, 1e-30f));
#pragma unroll
            for (int i = 0; i < 8; ++i) u[i] = y[i] * r;
        }
        // Rayleigh quotient
        float lam = 0.f;
#pragma unroll
        for (int i = 0; i < 8; ++i) {
            float acc = 0.f;
#pragma unroll
            for (int k = 0; k < 8; ++k) acc = fmaf(GU(i, k), u[k], acc);
            lam = fmaf(u[i], acc, lam);
        }
        const float pc1 = lam / (tr + 1e-8f);

        const float gate = 1.f / (1.f + expf(-cmr_gate[0]));
        const float kpg  = (kp[b] >= 5.0f) ? 1.5f : 1.0f;
        const float Gt   = gate * kpg;

        float eav[8], ecv[8];
#pragma unroll
        for (int i = 0; i < 8; ++i) {
            eav[i] = u[i] * rsig[i];            // p = sum a_s f[s,d] - bc
            ecv[i] = Gt * sig[i] * u[i];        // out = f - c_s * p
        }
        float ebc = 0.f;
#pragma unroll
        for (int i = 0; i < 8; ++i) ebc = fmaf(eav[i], mu[i], ebc);

        if (lane == 0) {
#pragma unroll
            for (int i = 0; i < 8; ++i) { cf[i] = eav[i]; cf[8 + i] = ecv[i]; }
            cf[16] = ebc;
            out[(size_t)Bn * BSTRIDE + b] = pc1;
            out[(size_t)Bn * BSTRIDE + Bn + b] =
                (pc1 >= 0.6f ? 1.f : 0.f) + (pc1 >= 0.8f ? 1.f : 0.f);
        }
    }
    __syncthreads();

    // ---- apply: streamed re-read (L3-hot) of this wave's D-half ----
    float av[8], cv[8];
#pragma unroll
    for (int s = 0; s < 8; ++s) { av[s] = cf[s]; cv[s] = cf[8 + s]; }
    const float bc = cf[16];

    float* __restrict__ ob = out + (size_t)b * BSTRIDE + w * HALF + lane * 2;

#pragma unroll
    for (int c = 0; c < NCH; ++c) {
        float2 x[8];
#pragma unroll
        for (int s = 0; s < 8; ++s)
            x[s] = *(const float2*)(fb + (size_t)s * DV + c * 128);

        float2 p = make_float2(-bc, -bc);
#pragma unroll
        for (int s = 0; s < 8; ++s) {
            p.x = fmaf(av[s], x[s].x, p.x);
            p.y = fmaf(av[s], x[s].y, p.y);
        }
#pragma unroll
        for (int s = 0; s < 8; ++s) {
            float2 o;
            o.x = fmaf(-cv[s], p.x, x[s].x);
            o.y = fmaf(-cv[s], p.y, x[s].y);
            *(float2*)(ob + (size_t)s * DV + c * 128) = o;
        }
    }
}

extern "C" void kernel_launch(void* const* d_in, const int* in_sizes, int n_in,
                              void* d_out, int out_size, void* d_ws, size_t ws_size,
                              hipStream_t stream) {
    const float* feat = (const float*)d_in[0];
    const float* kp   = (const float*)d_in[1];
    const float* gate = (const float*)d_in[2];
    float* out = (float*)d_out;
    const int Bn = in_sizes[0] / BSTRIDE;        // 2048
    (void)d_ws; (void)ws_size;

    cmr_dual<<<Bn, 128, 0, stream>>>(feat, kp, gate, out, Bn);
}